// Round 1
// baseline (1010.166 us; speedup 1.0000x reference)
//
#include <hip/hip_runtime.h>
#include <math.h>

// Problem constants (reference: S,B,I,H = 1024,512,5,32; G=4H=128)
#define S_LEN 1024
#define BATCH 512
#define HID   32

#define LOG2E 1.44269504088896340736f

__device__ __forceinline__ float fast_rcp(float x) { return __builtin_amdgcn_rcpf(x); }
__device__ __forceinline__ float fast_exp2(float x) { return __builtin_amdgcn_exp2f(x); }

// Fused 3-layer LSTM, software-pipelined across wave PAIRS.
// Block = 384 threads = 6 waves; wave-pair (w6>>1) = layer; blockIdx = batch elem.
// 512 blocks x 6 waves = 3072 waves = 12 waves/CU = 3 waves/SIMD (2x the old
// occupancy) to hide barrier/LDS/transcendental latency.
//
// Lane layout within a wave (half = w6&1 selects units 0-15 vs 16-31):
//   g4 = lane>>4 in {0:i, 1:f, 2:o, 3:g}; uu = lane&15; unit j = half*16+uu.
//   Each lane owns ONE gate row (32 whh + 32 wih weights in VGPRs).
// All weights/biases pre-scaled by log2e (g rows by 2*log2e) so every lane's
// activation is the SAME code: sigma = rcp(1 + exp2(-acc)); tanh(g) is
// recovered after the gather as 2*sigma(2g)-1.
// Gate gather: butterfly shfl_xor(16), shfl_xor(32) + 8 cndmask.
// h hand-off between layers via double-buffered LDS ring; ONE barrier per tick.
__global__ __launch_bounds__(384, 3)
void lstm3_fused(const float* __restrict__ x,
                 const float* __restrict__ Wih0, const float* __restrict__ Whh0,
                 const float* __restrict__ bih0, const float* __restrict__ bhh0,
                 const float* __restrict__ Wih1, const float* __restrict__ Whh1,
                 const float* __restrict__ bih1, const float* __restrict__ bhh1,
                 const float* __restrict__ Wih2, const float* __restrict__ Whh2,
                 const float* __restrict__ bih2, const float* __restrict__ bhh2,
                 float* __restrict__ hseq)
{
    const int b = blockIdx.x;
    const int w6 = threadIdx.x >> 6;      // 0..5
    const int layer = w6 >> 1;            // 0..2
    const int half = w6 & 1;              // units 0-15 vs 16-31
    const int l = threadIdx.x & 63;
    const int g4 = l >> 4;                // 0:i 1:f 2:o 3:g (our order)
    const int uu = l & 15;
    const int j = half * 16 + uu;         // unit 0..31
    const int tg = g4 ^ (g4 >> 1);        // torch gate idx: i=0,f=1,g=2,o=3
    const int row = tg * HID + j;         // row in G=128
    const bool sel1 = (g4 & 1) != 0;
    const bool sel2 = (g4 & 2) != 0;
    const bool isG = (g4 == 3);
    const float scale = isG ? (2.0f * LOG2E) : LOG2E;

    // ring[parity][slot][unit]; slot layer+1 holds that layer's h. Slot 0 unused.
    __shared__ float ring[2][4][HID];
    for (int i = threadIdx.x; i < 2 * 4 * HID; i += 384)
        (&ring[0][0][0])[i] = 0.0f;

    const float* Wih = (layer == 0) ? Wih0 : (layer == 1) ? Wih1 : Wih2;
    const float* Whh = (layer == 0) ? Whh0 : (layer == 1) ? Whh1 : Whh2;
    const float* bih = (layer == 0) ? bih0 : (layer == 1) ? bih1 : bih2;
    const float* bhh = (layer == 0) ? bhh0 : (layer == 1) ? bhh1 : bhh2;

    // One recurrent weight row per lane, pre-scaled (float4 loads, 128B-aligned)
    float whh[HID];
    {
        const float4* wr = reinterpret_cast<const float4*>(Whh + (size_t)row * HID);
#pragma unroll
        for (int k4 = 0; k4 < HID / 4; ++k4) {
            float4 v = wr[k4];
            whh[4 * k4 + 0] = v.x * scale;
            whh[4 * k4 + 1] = v.y * scale;
            whh[4 * k4 + 2] = v.z * scale;
            whh[4 * k4 + 3] = v.w * scale;
        }
    }
    float wih[HID];
    if (layer == 0) {
#pragma unroll
        for (int k = 0; k < 5; ++k)
            wih[k] = Wih[row * 5 + k] * scale;
    } else {
        const float4* wr = reinterpret_cast<const float4*>(Wih + (size_t)row * HID);
#pragma unroll
        for (int k4 = 0; k4 < HID / 4; ++k4) {
            float4 v = wr[k4];
            wih[4 * k4 + 0] = v.x * scale;
            wih[4 * k4 + 1] = v.y * scale;
            wih[4 * k4 + 2] = v.z * scale;
            wih[4 * k4 + 3] = v.w * scale;
        }
    }
    const float bias = (bih[row] + bhh[row]) * scale;

    float c = 0.0f;

    // Layer-0 waves: prefetch x[s=0] (all lanes same addresses -> L1 broadcast)
    const float* xb0 = x + (size_t)b * 5;
    float xv0 = 0.f, xv1 = 0.f, xv2 = 0.f, xv3 = 0.f, xv4 = 0.f;
    if (layer == 0) {
        xv0 = xb0[0]; xv1 = xb0[1]; xv2 = xb0[2]; xv3 = xb0[3]; xv4 = xb0[4];
    }

    __syncthreads();  // ring zero-init visible

    for (int t = 0; t < S_LEN + 2; ++t) {
        const int s = t - layer;
        const bool active = (s >= 0) && (s < S_LEN);
        const int p = t & 1;

        // ---- gate row dot: acc = bias + whh.h_own + wih.input (pre-scaled) ----
        float a0 = bias, a1 = 0.f, a2 = 0.f, a3 = 0.f;

        const float4* hown4 = reinterpret_cast<const float4*>(&ring[p][layer + 1][0]);
#pragma unroll
        for (int k4 = 0; k4 < HID / 4; ++k4) {
            float4 hv = hown4[k4];
            a0 += whh[4 * k4 + 0] * hv.x;
            a1 += whh[4 * k4 + 1] * hv.y;
            a2 += whh[4 * k4 + 2] * hv.z;
            a3 += whh[4 * k4 + 3] * hv.w;
        }

        if (layer == 0) {
            a0 += wih[0] * xv0;
            a1 += wih[1] * xv1;
            a2 += wih[2] * xv2;
            a3 += wih[3] * xv3;
            a0 += wih[4] * xv4;
            if (s + 1 < S_LEN) {
                const float* xn = xb0 + (size_t)(s + 1) * BATCH * 5;
                xv0 = xn[0]; xv1 = xn[1]; xv2 = xn[2]; xv3 = xn[3]; xv4 = xn[4];
            }
        } else {
            const float4* hin4 = reinterpret_cast<const float4*>(&ring[p][layer][0]);
#pragma unroll
            for (int k4 = 0; k4 < HID / 4; ++k4) {
                float4 hv = hin4[k4];
                a0 += wih[4 * k4 + 0] * hv.x;
                a1 += wih[4 * k4 + 1] * hv.y;
                a2 += wih[4 * k4 + 2] * hv.z;
                a3 += wih[4 * k4 + 3] * hv.w;
            }
        }
        const float acc = (a0 + a1) + (a2 + a3);

        // ---- uniform activation: sigma(x) for i,f,o; sigma(2g) for g lanes ----
        const float act = fast_rcp(1.0f + fast_exp2(-acc));

        // ---- butterfly gather: every lane gets all 4 activated gates of unit j
        const float v16 = __shfl_xor(act, 16);
        const float v32 = __shfl_xor(act, 32);
        const float v48 = __shfl_xor(v16, 32);
        const float t0 = sel1 ? v16 : act;
        const float t1 = sel1 ? act : v16;
        const float t2 = sel1 ? v48 : v32;
        const float t3 = sel1 ? v32 : v48;
        const float ii = sel2 ? t2 : t0;
        const float ff = sel2 ? t3 : t1;
        const float oo = sel2 ? t0 : t2;
        float gg = sel2 ? t1 : t3;
        gg = 2.0f * gg - 1.0f;            // tanh(g) = 2*sigma(2g) - 1

        const float c_new = ff * c + ii * gg;
        // tanh(c_new), overflow-safe
        const float e = fast_exp2(-2.0f * LOG2E * fabsf(c_new));
        const float tc = copysignf((1.0f - e) * fast_rcp(1.0f + e), c_new);
        const float h = oo * tc;

        if (active) {
            c = c_new;
            if (g4 == 0) {                // one gate-group writes (h replicated)
                ring[p ^ 1][layer + 1][j] = h;
                if (layer == 2)
                    hseq[((size_t)s * BATCH + b) * HID + j] = h;
            }
        }
        __syncthreads();  // tick boundary: writes(t) visible, reads(t) done
    }
}

// MLP head: per (s,b): y = relu(w3 . (W2 (W1 h + b1) + b2) + b3)
__global__ __launch_bounds__(256)
void mlp_kernel(const float* __restrict__ h, const float* __restrict__ w1,
                const float* __restrict__ b1, const float* __restrict__ w2,
                const float* __restrict__ b2, const float* __restrict__ w3,
                const float* __restrict__ b3, float* __restrict__ out)
{
    __shared__ float W1[HID * HID];
    __shared__ float W2[HID * HID];
    __shared__ float W3[HID];
    __shared__ float B1[HID];
    __shared__ float B2[HID];
    __shared__ float B3s;

    for (int i = threadIdx.x; i < HID * HID; i += blockDim.x) {
        W1[i] = w1[i];
        W2[i] = w2[i];
    }
    if (threadIdx.x < HID) {
        W3[threadIdx.x] = w3[threadIdx.x];
        B1[threadIdx.x] = b1[threadIdx.x];
        B2[threadIdx.x] = b2[threadIdx.x];
    }
    if (threadIdx.x == 0) B3s = b3[0];
    __syncthreads();

    const size_t e = (size_t)blockIdx.x * blockDim.x + threadIdx.x;  // (s*B+b)
    float hv[HID];
    const float4* hp = reinterpret_cast<const float4*>(h + e * HID);
#pragma unroll
    for (int k4 = 0; k4 < HID / 4; ++k4) {
        float4 v = hp[k4];
        hv[4 * k4 + 0] = v.x;
        hv[4 * k4 + 1] = v.y;
        hv[4 * k4 + 2] = v.z;
        hv[4 * k4 + 3] = v.w;
    }

    float y1[HID];
#pragma unroll
    for (int jj = 0; jj < HID; ++jj) {
        float acc = B1[jj];
#pragma unroll
        for (int k = 0; k < HID; ++k) acc += W1[jj * HID + k] * hv[k];
        y1[jj] = acc;
    }
    float y2[HID];
#pragma unroll
    for (int jj = 0; jj < HID; ++jj) {
        float acc = B2[jj];
#pragma unroll
        for (int k = 0; k < HID; ++k) acc += W2[jj * HID + k] * y1[k];
        y2[jj] = acc;
    }
    float acc3 = B3s;
#pragma unroll
    for (int k = 0; k < HID; ++k) acc3 += W3[k] * y2[k];
    out[e] = fmaxf(acc3, 0.0f);
}

extern "C" void kernel_launch(void* const* d_in, const int* in_sizes, int n_in,
                              void* d_out, int out_size, void* d_ws, size_t ws_size,
                              hipStream_t stream)
{
    const float* x    = (const float*)d_in[0];
    const float* Wih0 = (const float*)d_in[1];
    const float* Whh0 = (const float*)d_in[2];
    const float* bih0 = (const float*)d_in[3];
    const float* bhh0 = (const float*)d_in[4];
    const float* Wih1 = (const float*)d_in[5];
    const float* Whh1 = (const float*)d_in[6];
    const float* bih1 = (const float*)d_in[7];
    const float* bhh1 = (const float*)d_in[8];
    const float* Wih2 = (const float*)d_in[9];
    const float* Whh2 = (const float*)d_in[10];
    const float* bih2 = (const float*)d_in[11];
    const float* bhh2 = (const float*)d_in[12];
    const float* w1   = (const float*)d_in[13];
    const float* b1   = (const float*)d_in[14];
    const float* w2   = (const float*)d_in[15];
    const float* b2   = (const float*)d_in[16];
    const float* w3   = (const float*)d_in[17];
    const float* b3   = (const float*)d_in[18];

    // [S, BATCH, HID] fp32 buffer (64 MB) for layer-2 output
    float* hseq = (float*)d_ws;

    lstm3_fused<<<BATCH, 384, 0, stream>>>(x, Wih0, Whh0, bih0, bhh0,
                                           Wih1, Whh1, bih1, bhh1,
                                           Wih2, Whh2, bih2, bhh2, hseq);

    mlp_kernel<<<(S_LEN * BATCH) / 256, 256, 0, stream>>>(hseq, w1, b1, w2, b2, w3, b3,
                                                          (float*)d_out);
}